// Round 5
// baseline (496.361 us; speedup 1.0000x reference)
//
#include <hip/hip_runtime.h>
#include <hip/hip_bf16.h>
#include <cstdint>
#include <cstddef>

#define AS1 __attribute__((address_space(1)))
#define AS3 __attribute__((address_space(3)))

typedef __bf16 bf16x8 __attribute__((ext_vector_type(8)));
typedef float  floatx4 __attribute__((ext_vector_type(4)));

__device__ __forceinline__ void load_lds16(const void* g, void* l) {
    __builtin_amdgcn_global_load_lds((AS1 void*)g, (AS3 void*)l, 16, 0, 0);
}

__device__ __forceinline__ float fexp2(float x) { return __builtin_amdgcn_exp2f(x); }
__device__ __forceinline__ float flog2(float x) { return __builtin_amdgcn_logf(x); }

#define LOG2E 1.4426950408889634f
#define LN2   0.6931471805599453f
#define C0K   2.3052328943245633f   /* 0.5*log(2pi) + log(4) */

// single Gaussian logp in log2 domain
__device__ __forceinline__ float logp2(float xv, float mu, float al) {
    float e = fexp2(-al * LOG2E);
    float z = (xv - mu) * e;
    return (-0.5f * z * z - al - C0K) * LOG2E;
}
__device__ __forceinline__ float lse4(float a0, float a1, float a2, float a3) {
    float mx = fmaxf(fmaxf(a0, a1), fmaxf(a2, a3));
    return mx + flog2(fexp2(a0 - mx) + fexp2(a1 - mx) +
                      fexp2(a2 - mx) + fexp2(a3 - mx));
}
// (A o B)[r,c] = LSE_k(A[r,k] + B[k,c])   (log-semiring matmul, 4x4)
__device__ __forceinline__ void lmm4(const float* Aa, const float* Bb, float* D) {
#pragma unroll
    for (int r = 0; r < 4; ++r)
#pragma unroll
        for (int c = 0; c < 4; ++c)
            D[r * 4 + c] = lse4(Aa[r * 4 + 0] + Bb[0 * 4 + c],
                                Aa[r * 4 + 1] + Bb[1 * 4 + c],
                                Aa[r * 4 + 2] + Bb[2 * 4 + c],
                                Aa[r * 4 + 3] + Bb[3 * 4 + c]);
}

// ---------------------------------------------------------------------------
// Fused prep: all masks + fp32->bf16 in ONE launch.
// ---------------------------------------------------------------------------
__global__ __launch_bounds__(256)
void prep_all(const float* __restrict__ x,  const float* __restrict__ W0,
              const float* __restrict__ W1, const float* __restrict__ W2,
              const float* __restrict__ W3,
              __bf16* __restrict__ xb,  __bf16* __restrict__ w0m,
              __bf16* __restrict__ w1m, __bf16* __restrict__ w2m,
              __bf16* __restrict__ w3m)
{
    const int blk = blockIdx.x;
    const float* src; __bf16* dst; int shift, mode; long base;
    if (blk < 4096)        { src = x;  dst = xb;  shift = 7;  mode = 3; base = 0; }
    else if (blk < 5120)   { src = W0; dst = w0m; shift = 7;  mode = 0; base = 4096L * 256; }
    else if (blk < 21504)  { src = W1; dst = w1m; shift = 11; mode = 1; base = 5120L * 256; }
    else if (blk < 37888)  { src = W2; dst = w2m; shift = 11; mode = 1; base = 21504L * 256; }
    else                   { src = W3; dst = w3m; shift = 11; mode = 2; base = 37888L * 256; }
    long idx = (long)blk * 256 + threadIdx.x - base;
    int row = (int)(idx >> shift);
    int col = (int)(idx & ((1 << shift) - 1));
    float v = src[idx];
    bool keep = true;
    if (mode == 0)      keep = (row % 127) >= col;
    else if (mode == 1) keep = (row % 127) >= (col % 127);
    else if (mode == 2) keep = (row >> 5) > (col % 127);
    dst[idx] = (__bf16)(keep ? v : 0.0f);
}

// ---------------------------------------------------------------------------
// bf16 MFMA GEMM, C[M,N] = A[M,K] * Bw[N,K]^T + bias, optional ReLU.
// FUSE (GEMM3/theta): never materializes theta. Epilogue computes, per block
// (128 batches x 4 chain steps), the folded 4x4 log-semiring matrix ->
// P2[b][bn][16]; bn==0 also emits first-vector Fo[b][4], bn==31 last Lo[b][4].
// ---------------------------------------------------------------------------
template <bool RELU, bool OBF16, bool FUSE>
__global__ __launch_bounds__(256, 2)
void gemm_bt(const __bf16* __restrict__ A, const __bf16* __restrict__ Bw,
             const float* __restrict__ bias, void* __restrict__ Cout,
             int N, int K,
             const float* __restrict__ xg, float* __restrict__ P2,
             float* __restrict__ Fo, float* __restrict__ Lo)
{
    constexpr int SMEM = FUSE ? 34816 : 16384;   // FUSE: 128 cols * 68 dwords
    __shared__ __align__(16) char smem[SMEM];
    __bf16* lsA = (__bf16*)smem;                 // 8 KB
    __bf16* lsB = (__bf16*)(smem + 8192);        // 8 KB
    const int tid  = threadIdx.x;
    const int wave = tid >> 6;
    const int lane = tid & 63;
    const int bm = blockIdx.x, bn = blockIdx.y;
    const int wm = wave >> 1, wn = wave & 1;

    const int rsub = lane >> 2;
    const int cbx  = (lane & 3) ^ ((lane >> 3) & 3);
    const __bf16* gsrc[4];
    __bf16* ldst[4];
#pragma unroll
    for (int t = 0; t < 4; ++t) {
        int j = wave * 4 + t;
        if (j < 8) {
            int row = bm * 128 + j * 16 + rsub;
            gsrc[t] = A + (size_t)row * K + cbx * 8;
            ldst[t] = lsA + j * 512;
        } else {
            int jj = j - 8;
            int row = bn * 128 + jj * 16 + rsub;
            gsrc[t] = Bw + (size_t)row * K + cbx * 8;
            ldst[t] = lsB + jj * 512;
        }
    }

    const int fr   = lane & 15;
    const int ks   = lane >> 4;
    const int slot = ks ^ ((fr >> 1) & 3);
    const __bf16* ardp[4];
    const __bf16* brdp[4];
#pragma unroll
    for (int i = 0; i < 4; ++i) {
        ardp[i] = lsA + (wm * 64 + i * 16 + fr) * 32 + slot * 8;
        brdp[i] = lsB + (wn * 64 + i * 16 + fr) * 32 + slot * 8;
    }

    floatx4 acc[4][4];
    const floatx4 vzero = {0.f, 0.f, 0.f, 0.f};
#pragma unroll
    for (int mi = 0; mi < 4; ++mi)
#pragma unroll
        for (int ni = 0; ni < 4; ++ni) acc[mi][ni] = vzero;

    for (int kt = 0; kt < K; kt += 32) {
        __syncthreads();
#pragma unroll
        for (int t = 0; t < 4; ++t) {
            load_lds16((const void*)gsrc[t], (void*)ldst[t]);
            gsrc[t] += 32;
        }
        __syncthreads();
        bf16x8 af[4], bf[4];
#pragma unroll
        for (int i = 0; i < 4; ++i) af[i] = *(const bf16x8*)ardp[i];
#pragma unroll
        for (int i = 0; i < 4; ++i) bf[i] = *(const bf16x8*)brdp[i];
#pragma unroll
        for (int mi = 0; mi < 4; ++mi)
#pragma unroll
            for (int ni = 0; ni < 4; ++ni)
                acc[mi][ni] = __builtin_amdgcn_mfma_f32_16x16x32_bf16(
                    af[mi], bf[ni], acc[mi][ni], 0, 0, 0);
    }

    const int cn  = lane & 15;
    const int g16 = lane >> 4;
    const int cr4 = g16 * 4;

    if (!FUSE) {
#pragma unroll
        for (int ni = 0; ni < 4; ++ni) {
            int col = bn * 128 + wn * 64 + ni * 16 + cn;
            float bv = bias[col];
#pragma unroll
            for (int mi = 0; mi < 4; ++mi) {
                int row0 = bm * 128 + wm * 64 + mi * 16 + cr4;
#pragma unroll
                for (int q = 0; q < 4; ++q) {
                    float v = acc[mi][ni][q] + bv;
                    if (RELU) v = fmaxf(v, 0.f);
                    if (OBF16) ((__bf16*)Cout)[(size_t)(row0 + q) * N + col] = (__bf16)v;
                    else       ((float*)Cout)[(size_t)(row0 + q) * N + col] = v;
                }
            }
        }
    } else {
        // ---- fused chain epilogue. Two row-halves of 64 batches each.
        float* ldsC = (float*)smem;          // [col 0..127][68]: dword col*68+row
        float* Mex  = (float*)smem;          // [thread][20] (aliases ldsC, synced)
        const int sl = tid >> 6;             // step-in-block 0..3 (wave-uniform)
        const int bl = tid & 63;             // batch-in-half
        float Fv[4] = {0.f, 0.f, 0.f, 0.f};

        for (int h = 0; h < 2; ++h) {
            __syncthreads();                 // prior LDS use complete
            if (wm == h) {                   // these 2 waves hold rows [64h,64h+64)
#pragma unroll
                for (int ni = 0; ni < 4; ++ni) {
                    int col = wn * 64 + ni * 16 + cn;          // local col
                    float bv = bias[bn * 128 + col];
#pragma unroll
                    for (int mi = 0; mi < 4; ++mi) {
                        floatx4 v = acc[mi][ni];
                        v[0] += bv; v[1] += bv; v[2] += bv; v[3] += bv;
                        *(floatx4*)&ldsC[col * 68 + mi * 16 + cr4] = v;
                    }
                }
            }
            __syncthreads();

            const int bglob = bm * 128 + h * 64 + bl;
            const int sglob = 4 * bn + sl;
            const bool isF = (bn == 0  && sl == 0);   // step 0   -> first vector
            const bool isL = (bn == 31 && sl == 3);   // step 127 -> last vector
            float xv = xg[(size_t)bglob * 128 + sglob];

            float mu[16], al[16];
#pragma unroll
            for (int j = 0; j < 16; ++j) mu[j] = ldsC[(sl * 32 + j) * 68 + bl];
#pragma unroll
            for (int j = 0; j < 16; ++j) al[j] = ldsC[(sl * 32 + 16 + j) * 68 + bl];

            float Ms[16];
            if (isF || isL) {
#pragma unroll
                for (int j = 0; j < 16; ++j)
                    Ms[j] = ((j >> 2) == (j & 3)) ? 0.f : -1e30f;   // identity
            } else {
#pragma unroll
                for (int j = 0; j < 16; ++j) Ms[j] = logp2(xv, mu[j], al[j]);
            }
            if (isF) {
#pragma unroll
                for (int c = 0; c < 4; ++c) Fv[c] = logp2(xv, mu[c], al[c]);
            }
            if (isL) {
#pragma unroll
                for (int r = 0; r < 4; ++r)
                    Lo[(size_t)bglob * 4 + r] = logp2(xv, mu[4 * r], al[4 * r]);
            }

            __syncthreads();                 // ldsC reads done; Mex may alias
#pragma unroll
            for (int k = 0; k < 4; ++k)
                *(floatx4*)&Mex[tid * 20 + k * 4] =
                    *(floatx4*)&Ms[k * 4];
            __syncthreads();

            float M2[16];
            if ((sl & 1) == 0) {             // sl0: s0*s1 ; sl2: s2*s3
                float Mp[16];
#pragma unroll
                for (int k = 0; k < 4; ++k)
                    *(floatx4*)&Mp[k * 4] = *(const floatx4*)&Mex[(tid + 64) * 20 + k * 4];
                lmm4(Ms, Mp, M2);
            }
            __syncthreads();
            if (sl == 2) {
#pragma unroll
                for (int k = 0; k < 4; ++k)
                    *(floatx4*)&Mex[tid * 20 + k * 4] = *(floatx4*)&M2[k * 4];
            }
            __syncthreads();
            if (sl == 0) {
                float Mq[16], Mf[16];
#pragma unroll
                for (int k = 0; k < 4; ++k)
                    *(floatx4*)&Mq[k * 4] = *(const floatx4*)&Mex[(tid + 128) * 20 + k * 4];
                lmm4(M2, Mq, Mf);
                float* dst = P2 + ((size_t)bglob * 32 + bn) * 16;
#pragma unroll
                for (int k = 0; k < 4; ++k)
                    *(floatx4*)&dst[k * 4] = *(floatx4*)&Mf[k * 4];
                if (bn == 0) {
#pragma unroll
                    for (int c = 0; c < 4; ++c) Fo[(size_t)bglob * 4 + c] = Fv[c];
                }
            }
        }
    }
}

// ---------------------------------------------------------------------------
// Combine: fold 32 block matrices + first/last boundary vectors per batch.
// 4 lanes per batch (lane r = row r), shuffles for the row exchange.
// ---------------------------------------------------------------------------
__global__ __launch_bounds__(256)
void chain_fin(const float* __restrict__ P2,   // [8192,32,16]
               const float* __restrict__ Fo,   // [8192,4]
               const float* __restrict__ Lo,   // [8192,4]
               float* __restrict__ out)        // [8192]
{
    const int tid  = threadIdx.x;
    const int lane = tid & 63;
    const int r    = lane & 3;
    const int l0   = lane & 60;
    const int b    = blockIdx.x * 64 + (tid >> 2);

    const float* Pb = P2 + (size_t)b * 512;      // 32*16
    floatx4 m0 = *(const floatx4*)(Pb + r * 4);
    float M[4] = {m0[0], m0[1], m0[2], m0[3]};

#pragma unroll
    for (int s = 1; s < 32; ++s) {
        floatx4 lr = *(const floatx4*)(Pb + s * 16 + r * 4);
        float Mn[4];
#pragma unroll
        for (int c = 0; c < 4; ++c) {
            float a0 = M[0] + __shfl(lr[c], l0 + 0);
            float a1 = M[1] + __shfl(lr[c], l0 + 1);
            float a2 = M[2] + __shfl(lr[c], l0 + 2);
            float a3 = M[3] + __shfl(lr[c], l0 + 3);
            Mn[c] = lse4(a0, a1, a2, a3);
        }
#pragma unroll
        for (int k = 0; k < 4; ++k) M[k] = Mn[k];
    }

    // t[r] = lse_c(M[r][c] + last[c])
    floatx4 Lv = *(const floatx4*)(Lo + (size_t)b * 4);
    float tr = lse4(M[0] + Lv[0], M[1] + Lv[1], M[2] + Lv[2], M[3] + Lv[3]);

    // out = lse_r(first[r] + t[r])
    float v = Fo[(size_t)b * 4 + r] + tr;
    float m1 = fmaxf(v, __shfl_xor(v, 1));
    float m2 = fmaxf(m1, __shfl_xor(m1, 2));
    float sum = fexp2(v - m2);
    sum += __shfl_xor(sum, 1);
    sum += __shfl_xor(sum, 2);
    if (r == 0) out[b] = (m2 + flog2(sum)) * LN2;
}

// ---------------------------------------------------------------------------
extern "C" void kernel_launch(void* const* d_in, const int* in_sizes, int n_in,
                              void* d_out, int out_size, void* d_ws, size_t ws_size,
                              hipStream_t stream)
{
    (void)in_sizes; (void)n_in; (void)out_size; (void)ws_size;
    const float* x  = (const float*)d_in[0];
    const float* W0 = (const float*)d_in[1];
    const float* b0 = (const float*)d_in[2];
    const float* W1 = (const float*)d_in[3];
    const float* b1 = (const float*)d_in[4];
    const float* W2 = (const float*)d_in[5];
    const float* b2 = (const float*)d_in[6];
    const float* W3 = (const float*)d_in[7];
    const float* b3 = (const float*)d_in[8];

    char* ws = (char*)d_ws;
    size_t off = 0;
    auto alloc = [&](size_t bytes) { char* p = ws + off; off += bytes; return p; };
    __bf16* xb  = (__bf16*)alloc((size_t)8192 * 128 * 2);    // 2 MB
    __bf16* w0m = (__bf16*)alloc((size_t)2048 * 128 * 2);    // 0.5 MB
    __bf16* w1m = (__bf16*)alloc((size_t)2048 * 2048 * 2);   // 8 MB
    __bf16* w2m = (__bf16*)alloc((size_t)2048 * 2048 * 2);   // 8 MB
    __bf16* w3m = (__bf16*)alloc((size_t)4096 * 2048 * 2);   // 16 MB
    __bf16* h1  = (__bf16*)alloc((size_t)8192 * 2048 * 2);   // 32 MB
    __bf16* h2  = (__bf16*)alloc((size_t)8192 * 2048 * 2);   // 32 MB
    __bf16* h3  = h1;                  // h1 dead after GEMM2; reuse for h3
    float*  P2  = (float*)h2;          // h2 dead after GEMM2 output consumed
    float*  Fo  = P2 + (size_t)8192 * 32 * 16;   // P2 = 16.8 MB
    float*  Lo  = Fo + (size_t)8192 * 4;         // F/L = 131 KB each, all < 32 MB

    // fused masked-weight + x prep (single launch)
    prep_all<<<70656, 256, 0, stream>>>(x, W0, W1, W2, W3, xb, w0m, w1m, w2m, w3m);

    // 3 hidden GEMMs: C[8192,N] = relu(A * W^T + b) -> bf16
    gemm_bt<true, true, false><<<dim3(64, 16), 256, 0, stream>>>(
        xb, w0m, b0, h1, 2048, 128, nullptr, nullptr, nullptr, nullptr);
    gemm_bt<true, true, false><<<dim3(64, 16), 256, 0, stream>>>(
        h1, w1m, b1, h2, 2048, 2048, nullptr, nullptr, nullptr, nullptr);
    gemm_bt<true, true, false><<<dim3(64, 16), 256, 0, stream>>>(
        h2, w2m, b2, h3, 2048, 2048, nullptr, nullptr, nullptr, nullptr);

    // GEMM3 fused with per-block 4-step log-semiring fold (theta never stored)
    gemm_bt<false, false, true><<<dim3(64, 32), 256, 0, stream>>>(
        h3, w3m, b3, nullptr, 4096, 2048, x, P2, Fo, Lo);

    // fold 32 segment matrices + boundaries
    chain_fin<<<128, 256, 0, stream>>>(P2, Fo, Lo, (float*)d_out);
}

// Round 6
// 389.123 us; speedup vs baseline: 1.2756x; 1.2756x over previous
//
#include <hip/hip_runtime.h>
#include <hip/hip_bf16.h>
#include <cstdint>
#include <cstddef>

#define AS1 __attribute__((address_space(1)))
#define AS3 __attribute__((address_space(3)))

typedef __bf16 bf16x8 __attribute__((ext_vector_type(8)));
typedef float  floatx4 __attribute__((ext_vector_type(4)));

__device__ __forceinline__ void load_lds16(const void* g, void* l) {
    __builtin_amdgcn_global_load_lds((AS1 void*)g, (AS3 void*)l, 16, 0, 0);
}

__device__ __forceinline__ float fexp2(float x) { return __builtin_amdgcn_exp2f(x); }
__device__ __forceinline__ float flog2(float x) { return __builtin_amdgcn_logf(x); }

// Degree-sorted feature permutation for hidden layers (2048 feats, deg = f%127).
// sorted position p <-> feature f: p = (f%127)*16 + f/127 for f<2032 (=16*127),
// p = f for f>=2032. res(p) = degree of the feature at sorted position p.
__device__ __forceinline__ int invp(int p) {
    return p < 2032 ? (p & 15) * 127 + (p >> 4) : p;
}
__device__ __forceinline__ int resp(int p) {
    return p < 2032 ? (p >> 4) : p - 2032;
}

// ---------------------------------------------------------------------------
// Fused prep: all masks + fp32->bf16 + degree-sort permutation, ONE launch.
// Outputs are in SORTED coordinates:
//   xb  [8192,128]  natural (copy)
//   w0m [p_n, c]     = W0[invp(p_n), c]          * (res(p_n) >= c)
//   w1m [p_n, p_k]   = W1[invp(p_n), invp(p_k)]  * (res(p_n) >= res(p_k))
//   w2m  same as w1m
//   w3m [n, p_k]     = W3[n, invp(p_k)]          * ((n>>5) > res(p_k))
// ---------------------------------------------------------------------------
__global__ __launch_bounds__(256)
void prep_all(const float* __restrict__ x,  const float* __restrict__ W0,
              const float* __restrict__ W1, const float* __restrict__ W2,
              const float* __restrict__ W3,
              __bf16* __restrict__ xb,  __bf16* __restrict__ w0m,
              __bf16* __restrict__ w1m, __bf16* __restrict__ w2m,
              __bf16* __restrict__ w3m)
{
    const int blk = blockIdx.x;
    const float* src; __bf16* dst; int shift, mode; long base;
    if (blk < 4096)        { src = x;  dst = xb;  shift = 7;  mode = 3; base = 0; }
    else if (blk < 5120)   { src = W0; dst = w0m; shift = 7;  mode = 0; base = 4096L * 256; }
    else if (blk < 21504)  { src = W1; dst = w1m; shift = 11; mode = 1; base = 5120L * 256; }
    else if (blk < 37888)  { src = W2; dst = w2m; shift = 11; mode = 1; base = 21504L * 256; }
    else                   { src = W3; dst = w3m; shift = 11; mode = 2; base = 37888L * 256; }
    long idx = (long)blk * 256 + threadIdx.x - base;   // dst-linear (sorted space)
    int row = (int)(idx >> shift);
    int col = (int)(idx & ((1 << shift) - 1));
    float v; bool keep;
    if (mode == 3)      { v = src[idx];                                  keep = true; }
    else if (mode == 0) { v = src[(long)invp(row) * 128 + col];          keep = resp(row) >= col; }
    else if (mode == 1) { v = src[(long)invp(row) * 2048 + invp(col)];   keep = resp(row) >= resp(col); }
    else                { v = src[(long)row * 2048 + invp(col)];         keep = (row >> 5) > resp(col); }
    dst[idx] = (__bf16)(keep ? v : 0.0f);
}

// ---------------------------------------------------------------------------
// bf16 MFMA GEMM, C[M,N] = A[M,K] * Bw[N,K]^T + bias, optional ReLU.
// K-SKIP: per N-tile bn, only chunks [0, limit) are nonzero in sorted space,
//   limit = min(NK, (klm*bn + kla) >> kls); if tail && limit<NK, also run
//   chunk NK-1 (holds the 16 leftover low-degree features).
// TLAYOUT: store fp32 batch-interleaved th2[b>>6][col][b&63].
// PERMBIAS: bias indexed through invp(col) (output cols are degree-sorted).
// ---------------------------------------------------------------------------
template <bool RELU, bool OBF16, bool TLAYOUT, bool PERMBIAS>
__global__ __launch_bounds__(256, 2)
void gemm_bt(const __bf16* __restrict__ A, const __bf16* __restrict__ Bw,
             const float* __restrict__ bias, void* __restrict__ Cout,
             int N, int K, int klm, int kla, int kls, int tail)
{
    __shared__ __align__(16) __bf16 lsA[128 * 32];
    __shared__ __align__(16) __bf16 lsB[128 * 32];
    const int tid  = threadIdx.x;
    const int wave = tid >> 6;
    const int lane = tid & 63;
    const int bm = blockIdx.x, bn = blockIdx.y;
    const int wm = wave >> 1, wn = wave & 1;

    const int rsub = lane >> 2;
    const int cbx  = (lane & 3) ^ ((lane >> 3) & 3);
    const __bf16* gsrc[4];
    __bf16* ldst[4];
#pragma unroll
    for (int t = 0; t < 4; ++t) {
        int j = wave * 4 + t;
        if (j < 8) {
            int row = bm * 128 + j * 16 + rsub;
            gsrc[t] = A + (size_t)row * K + cbx * 8;
            ldst[t] = lsA + j * 512;
        } else {
            int jj = j - 8;
            int row = bn * 128 + jj * 16 + rsub;
            gsrc[t] = Bw + (size_t)row * K + cbx * 8;
            ldst[t] = lsB + jj * 512;
        }
    }

    const int fr   = lane & 15;
    const int ks   = lane >> 4;
    const int slot = ks ^ ((fr >> 1) & 3);
    const __bf16* ardp[4];
    const __bf16* brdp[4];
#pragma unroll
    for (int i = 0; i < 4; ++i) {
        ardp[i] = lsA + (wm * 64 + i * 16 + fr) * 32 + slot * 8;
        brdp[i] = lsB + (wn * 64 + i * 16 + fr) * 32 + slot * 8;
    }

    floatx4 acc[4][4];
    const floatx4 vzero = {0.f, 0.f, 0.f, 0.f};
#pragma unroll
    for (int mi = 0; mi < 4; ++mi)
#pragma unroll
        for (int ni = 0; ni < 4; ++ni) acc[mi][ni] = vzero;

    const int nk = K >> 5;
    int limit = (klm * bn + kla) >> kls;
    if (limit > nk) limit = nk;
    const int iters = limit + ((tail && limit < nk) ? 1 : 0);

    for (int it = 0; it < iters; ++it) {
        const int kt = (it < limit ? it : nk - 1) << 5;
        __syncthreads();
#pragma unroll
        for (int t = 0; t < 4; ++t)
            load_lds16((const void*)(gsrc[t] + kt), (void*)ldst[t]);
        __syncthreads();
        bf16x8 af[4], bf[4];
#pragma unroll
        for (int i = 0; i < 4; ++i) af[i] = *(const bf16x8*)ardp[i];
#pragma unroll
        for (int i = 0; i < 4; ++i) bf[i] = *(const bf16x8*)brdp[i];
#pragma unroll
        for (int mi = 0; mi < 4; ++mi)
#pragma unroll
            for (int ni = 0; ni < 4; ++ni)
                acc[mi][ni] = __builtin_amdgcn_mfma_f32_16x16x32_bf16(
                    af[mi], bf[ni], acc[mi][ni], 0, 0, 0);
    }

    const int cn  = lane & 15;
    const int cr4 = (lane >> 4) * 4;
#pragma unroll
    for (int ni = 0; ni < 4; ++ni) {
        int col = bn * 128 + wn * 64 + ni * 16 + cn;
        float bv = bias[PERMBIAS ? invp(col) : col];
#pragma unroll
        for (int mi = 0; mi < 4; ++mi) {
            int row0 = bm * 128 + wm * 64 + mi * 16 + cr4;
#pragma unroll
            for (int q = 0; q < 4; ++q) {
                float v = acc[mi][ni][q] + bv;
                if (RELU) v = fmaxf(v, 0.f);
                if (TLAYOUT) {
                    // b = row0+q; b>>6 = bm*2+wm; b&63 = mi*16+cr4+q
                    size_t addr = (size_t)(bm * 2 + wm) * ((size_t)N * 64)
                                + (size_t)col * 64 + (mi * 16 + cr4 + q);
                    ((float*)Cout)[addr] = v;
                } else if (OBF16) {
                    ((__bf16*)Cout)[(size_t)(row0 + q) * N + col] = (__bf16)v;
                } else {
                    ((float*)Cout)[(size_t)(row0 + q) * N + col] = v;
                }
            }
        }
    }
}

// ---------------------------------------------------------------------------
// Segment-parallel log-semiring chain, one thread per (batch, segment).
// theta in batch-interleaved layout th2[b>>6][f][b&63].
// ---------------------------------------------------------------------------
__global__ __launch_bounds__(256)
void chain_seg(const float* __restrict__ th2,   // [128][4096][64]
               const float* __restrict__ x,     // [8192,128]
               float* __restrict__ P)           // [8192,18,16]
{
    const int b = blockIdx.x * 256 + threadIdx.x;
    const int s = blockIdx.y;                    // 0..17
    const int i0 = 1 + s * 7;
    const float* tp = th2 + (size_t)(b >> 6) * (4096 * 64) + (b & 63)
                          + (size_t)i0 * 32 * 64;
    const float* xp = x + (size_t)b * 128 + i0;

    const float LOG2E = 1.4426950408889634f;
    const float C0    = 2.3052328943245633f;     // 0.5*log(2pi) + log(4)

    float M[4][4];
#pragma unroll
    for (int r = 0; r < 4; ++r)
#pragma unroll
        for (int c = 0; c < 4; ++c) M[r][c] = (r == c) ? 0.f : -1e30f;

    for (int ii = 0; ii < 7; ++ii) {
        float mu[16], al[16];
#pragma unroll
        for (int j = 0; j < 16; ++j) mu[j] = tp[(size_t)j * 64];
#pragma unroll
        for (int j = 0; j < 16; ++j) al[j] = tp[(size_t)(16 + j) * 64];
        float xv = xp[ii];
        tp += 32 * 64;
        float lp[16];
#pragma unroll
        for (int j = 0; j < 16; ++j) {
            float a = al[j];
            float e = fexp2(-a * LOG2E);
            float z = (xv - mu[j]) * e;
            lp[j] = (-0.5f * z * z - a - C0) * LOG2E;
        }
        float Mn[4][4];
#pragma unroll
        for (int r = 0; r < 4; ++r)
#pragma unroll
            for (int c = 0; c < 4; ++c) {
                float a0 = M[r][0] + lp[0 * 4 + c];
                float a1 = M[r][1] + lp[1 * 4 + c];
                float a2 = M[r][2] + lp[2 * 4 + c];
                float a3 = M[r][3] + lp[3 * 4 + c];
                float mx = fmaxf(fmaxf(a0, a1), fmaxf(a2, a3));
                float sm = fexp2(a0 - mx) + fexp2(a1 - mx) +
                           fexp2(a2 - mx) + fexp2(a3 - mx);
                Mn[r][c] = mx + flog2(sm);
            }
#pragma unroll
        for (int r = 0; r < 4; ++r)
#pragma unroll
            for (int c = 0; c < 4; ++c) M[r][c] = Mn[r][c];
    }

    float* pb = P + ((size_t)b * 18 + s) * 16;
#pragma unroll
    for (int r = 0; r < 4; ++r) {
        floatx4 o = {M[r][0], M[r][1], M[r][2], M[r][3]};
        *(floatx4*)(pb + r * 4) = o;
    }
}

// ---------------------------------------------------------------------------
// Combine: fold 18 segment matrices + first/last boundary vectors per batch.
// ---------------------------------------------------------------------------
__global__ __launch_bounds__(256)
void chain_fin(const float* __restrict__ th2,   // [128][4096][64]
               const float* __restrict__ x,     // [8192,128]
               const float* __restrict__ P,     // [8192,18,16]
               float* __restrict__ out)         // [8192]
{
    const int tid  = threadIdx.x;
    const int lane = tid & 63;
    const int r    = lane & 3;
    const int l0   = lane & 60;
    const int b    = blockIdx.x * 64 + (tid >> 2);
    const float* tb = th2 + (size_t)(b >> 6) * (4096 * 64) + (b & 63);

    const float LOG2E = 1.4426950408889634f;
    const float LN2   = 0.6931471805599453f;
    const float C0    = 2.3052328943245633f;

    const float* Pb = P + (size_t)b * 288;       // 18*16
    floatx4 m0 = *(const floatx4*)(Pb + r * 4);
    float M[4] = {m0[0], m0[1], m0[2], m0[3]};

#pragma unroll
    for (int s = 1; s < 18; ++s) {
        floatx4 lr = *(const floatx4*)(Pb + s * 16 + r * 4);
        float Mn[4];
#pragma unroll
        for (int c = 0; c < 4; ++c) {
            float a0 = M[0] + __shfl(lr[c], l0 + 0);
            float a1 = M[1] + __shfl(lr[c], l0 + 1);
            float a2 = M[2] + __shfl(lr[c], l0 + 2);
            float a3 = M[3] + __shfl(lr[c], l0 + 3);
            float mx = fmaxf(fmaxf(a0, a1), fmaxf(a2, a3));
            float sm = fexp2(a0 - mx) + fexp2(a1 - mx) + fexp2(a2 - mx) + fexp2(a3 - mx);
            Mn[c] = mx + flog2(sm);
        }
#pragma unroll
        for (int k = 0; k < 4; ++k) M[k] = Mn[k];
    }

    float xl = x[(size_t)b * 128 + 127];
    float a[4];
#pragma unroll
    for (int c = 0; c < 4; ++c) {
        float mu_ = tb[(size_t)(4064 + c * 4) * 64];
        float al_ = tb[(size_t)(4064 + 16 + c * 4) * 64];
        float e = fexp2(-al_ * LOG2E);
        float z = (xl - mu_) * e;
        float lp2 = (-0.5f * z * z - al_ - C0) * LOG2E;
        a[c] = M[c] + lp2;
    }
    float mx = fmaxf(fmaxf(a[0], a[1]), fmaxf(a[2], a[3]));
    float tr = mx + flog2(fexp2(a[0] - mx) + fexp2(a[1] - mx) +
                          fexp2(a[2] - mx) + fexp2(a[3] - mx));

    float x0  = x[(size_t)b * 128];
    float muf = tb[(size_t)r * 64];
    float alf = tb[(size_t)(16 + r) * 64];
    float ef = fexp2(-alf * LOG2E);
    float zf = (x0 - muf) * ef;
    float f2 = (-0.5f * zf * zf - alf - C0) * LOG2E;
    float v = f2 + tr;
    float m1 = fmaxf(v, __shfl_xor(v, 1));
    float m2 = fmaxf(m1, __shfl_xor(m1, 2));
    float sum = fexp2(v - m2);
    sum += __shfl_xor(sum, 1);
    sum += __shfl_xor(sum, 2);
    if (r == 0) out[b] = (m2 + flog2(sum)) * LN2;
}

// ---------------------------------------------------------------------------
extern "C" void kernel_launch(void* const* d_in, const int* in_sizes, int n_in,
                              void* d_out, int out_size, void* d_ws, size_t ws_size,
                              hipStream_t stream)
{
    (void)in_sizes; (void)n_in; (void)out_size; (void)ws_size;
    const float* x  = (const float*)d_in[0];
    const float* W0 = (const float*)d_in[1];
    const float* b0 = (const float*)d_in[2];
    const float* W1 = (const float*)d_in[3];
    const float* b1 = (const float*)d_in[4];
    const float* W2 = (const float*)d_in[5];
    const float* b2 = (const float*)d_in[6];
    const float* W3 = (const float*)d_in[7];
    const float* b3 = (const float*)d_in[8];

    char* ws = (char*)d_ws;
    size_t off = 0;
    auto alloc = [&](size_t bytes) { char* p = ws + off; off += bytes; return p; };
    __bf16* xb  = (__bf16*)alloc((size_t)8192 * 128 * 2);    // 2 MB
    __bf16* w0m = (__bf16*)alloc((size_t)2048 * 128 * 2);    // 0.5 MB
    __bf16* w1m = (__bf16*)alloc((size_t)2048 * 2048 * 2);   // 8 MB
    __bf16* w2m = (__bf16*)alloc((size_t)2048 * 2048 * 2);   // 8 MB
    __bf16* w3m = (__bf16*)alloc((size_t)4096 * 2048 * 2);   // 16 MB
    __bf16* h1  = (__bf16*)alloc((size_t)8192 * 2048 * 2);   // 32 MB
    __bf16* h2  = (__bf16*)alloc((size_t)8192 * 2048 * 2);   // 32 MB
    float*  th  = (float*) alloc((size_t)8192 * 4096 * 4);   // 128 MB (batch-interleaved)
    __bf16* h3  = h1;            // h1 dead after GEMM2; reuse for h3
    float*  P   = (float*)h2;    // h2 dead after GEMM3; P = 9.4 MB << 32 MB

    // fused masked+degree-sorted weight prep (single launch)
    prep_all<<<70656, 256, 0, stream>>>(x, W0, W1, W2, W3, xb, w0m, w1m, w2m, w3m);

    // GEMM0: K=128 natural cols; limit = (8*bn+39)>>5 chunks, no tail
    gemm_bt<true, true, false, true><<<dim3(64, 16), 256, 0, stream>>>(
        xb, w0m, b0, h1, 2048, 128, 8, 39, 5, 0);
    // GEMM1/2: sorted K; limit = 4*bn+4 chunks (+tail)
    gemm_bt<true, true, false, true><<<dim3(64, 16), 256, 0, stream>>>(
        h1, w1m, b1, h2, 2048, 2048, 4, 4, 0, 1);
    gemm_bt<true, true, false, true><<<dim3(64, 16), 256, 0, stream>>>(
        h2, w2m, b2, h3, 2048, 2048, 4, 4, 0, 1);
    // GEMM3: theta (natural N, TLAYOUT store); limit = 2*bn+2 chunks (+tail)
    gemm_bt<false, false, true, false><<<dim3(64, 32), 256, 0, stream>>>(
        h3, w3m, b3, th, 4096, 2048, 2, 2, 0, 1);

    // segment-parallel log-semiring chain
    chain_seg<<<dim3(32, 18), 256, 0, stream>>>(th, x, P);
    chain_fin<<<128, 256, 0, stream>>>(th, x, P, (float*)d_out);
}

// Round 7
// 357.603 us; speedup vs baseline: 1.3880x; 1.0881x over previous
//
#include <hip/hip_runtime.h>
#include <hip/hip_bf16.h>
#include <cstdint>
#include <cstddef>

#define AS1 __attribute__((address_space(1)))
#define AS3 __attribute__((address_space(3)))

typedef __bf16 bf16x8 __attribute__((ext_vector_type(8)));
typedef float  floatx4 __attribute__((ext_vector_type(4)));

__device__ __forceinline__ void load_lds16(const void* g, void* l) {
    __builtin_amdgcn_global_load_lds((AS1 void*)g, (AS3 void*)l, 16, 0, 0);
}

__device__ __forceinline__ float fexp2(float x) { return __builtin_amdgcn_exp2f(x); }
__device__ __forceinline__ float flog2(float x) { return __builtin_amdgcn_logf(x); }

// Degree-sorted feature permutation for hidden layers (2048 feats, deg = f%127).
// sorted position p <-> feature f: p = (f%127)*16 + f/127 for f<2032 (=16*127),
// p = f for f>=2032. resp(p) = degree of the feature at sorted position p.
__device__ __forceinline__ int invp(int p) {
    return p < 2032 ? (p & 15) * 127 + (p >> 4) : p;
}
__device__ __forceinline__ int resp(int p) {
    return p < 2032 ? (p >> 4) : p - 2032;
}

// ---------------------------------------------------------------------------
// Prep v3: masks + fp32->bf16 + degree-sort, coalesced both sides via LDS.
// 2048 elements per block (256 thr x 8). Regions:
//   [0,512)      x copy          [512,640)    W0 (row-perm only)
//   [640,2688)   W1 row-per-block (LDS col permute)
//   [2688,4736)  W2 row-per-block
//   [4736,8832)  W3 row-per-block (natural rows, col permute)
// ---------------------------------------------------------------------------
__global__ __launch_bounds__(256)
void prep_all(const float* __restrict__ x,  const float* __restrict__ W0,
              const float* __restrict__ W1, const float* __restrict__ W2,
              const float* __restrict__ W3,
              __bf16* __restrict__ xb,  __bf16* __restrict__ w0m,
              __bf16* __restrict__ w1m, __bf16* __restrict__ w2m,
              __bf16* __restrict__ w3m)
{
    __shared__ float lds[2048];
    const int blk = blockIdx.x;
    const int tid = threadIdx.x;
    const int t8  = tid * 8;

    if (blk < 640) {                       // direct regions (x, W0)
        bf16x8 o;
        if (blk < 512) {                   // x copy
            size_t base = (size_t)blk * 2048 + t8;
            floatx4 a = *(const floatx4*)(x + base);
            floatx4 b = *(const floatx4*)(x + base + 4);
#pragma unroll
            for (int j = 0; j < 4; ++j) { o[j] = (__bf16)a[j]; o[4 + j] = (__bf16)b[j]; }
            *(bf16x8*)(xb + base) = o;
        } else {                           // W0: dst[p_n][c] = W0[invp(p_n)][c] * mask
            long idx = (long)(blk - 512) * 2048 + t8;
            int p_n = (int)(idx >> 7);
            int c   = (int)(idx & 127);
            int dg  = resp(p_n);
            const float* s = W0 + (long)invp(p_n) * 128 + c;
            floatx4 a = *(const floatx4*)s;
            floatx4 b = *(const floatx4*)(s + 4);
#pragma unroll
            for (int j = 0; j < 8; ++j) {
                float v = j < 4 ? a[j] : b[j - 4];
                o[j] = (__bf16)((dg >= c + j) ? v : 0.0f);
            }
            *(bf16x8*)(w0m + idx) = o;
        }
        return;
    }

    // permuted-column regions: one dst row per block
    const float* srow; __bf16* drow; int deg_n; bool strict;
    if (blk < 2688) {
        int p_n = blk - 640;
        srow = W1 + (size_t)invp(p_n) * 2048; drow = w1m + (size_t)p_n * 2048;
        deg_n = resp(p_n); strict = false;
    } else if (blk < 4736) {
        int p_n = blk - 2688;
        srow = W2 + (size_t)invp(p_n) * 2048; drow = w2m + (size_t)p_n * 2048;
        deg_n = resp(p_n); strict = false;
    } else {
        int n = blk - 4736;
        srow = W3 + (size_t)n * 2048; drow = w3m + (size_t)n * 2048;
        deg_n = n >> 5; strict = true;
    }
    // coalesced read of the whole source row into LDS (natural f order)
    floatx4 a = *(const floatx4*)(srow + t8);
    floatx4 b = *(const floatx4*)(srow + t8 + 4);
    *(floatx4*)&lds[t8]     = a;
    *(floatx4*)&lds[t8 + 4] = b;
    __syncthreads();
    bf16x8 o;
#pragma unroll
    for (int j = 0; j < 8; ++j) {
        int p = t8 + j;
        float v = lds[invp(p)];
        int dg = resp(p);
        bool keep = strict ? (deg_n > dg) : (deg_n >= dg);
        o[j] = (__bf16)(keep ? v : 0.0f);
    }
    *(bf16x8*)(drow + t8) = o;
}

// ---------------------------------------------------------------------------
// bf16 MFMA GEMM, C[M,N] = A[M,K] * Bw[N,K]^T + bias, optional ReLU.
// K-SKIP: chunks [0,limit) + tail chunk NK-1 (low-degree leftovers).
// TLAYOUT: store bf16 batch-interleaved th2[b>>6][col][b&63].
// PERMBIAS: bias indexed through invp(col).
// ---------------------------------------------------------------------------
template <bool RELU, bool OBF16, bool TLAYOUT, bool PERMBIAS>
__global__ __launch_bounds__(256, 4)
void gemm_bt(const __bf16* __restrict__ A, const __bf16* __restrict__ Bw,
             const float* __restrict__ bias, void* __restrict__ Cout,
             int N, int K, int klm, int kla, int kls, int tail)
{
    __shared__ __align__(16) __bf16 lsA[128 * 32];
    __shared__ __align__(16) __bf16 lsB[128 * 32];
    const int tid  = threadIdx.x;
    const int wave = tid >> 6;
    const int lane = tid & 63;
    const int bm = blockIdx.x, bn = blockIdx.y;
    const int wm = wave >> 1, wn = wave & 1;

    const int rsub = lane >> 2;
    const int cbx  = (lane & 3) ^ ((lane >> 3) & 3);
    const __bf16* gsrc[4];
    __bf16* ldst[4];
#pragma unroll
    for (int t = 0; t < 4; ++t) {
        int j = wave * 4 + t;
        if (j < 8) {
            int row = bm * 128 + j * 16 + rsub;
            gsrc[t] = A + (size_t)row * K + cbx * 8;
            ldst[t] = lsA + j * 512;
        } else {
            int jj = j - 8;
            int row = bn * 128 + jj * 16 + rsub;
            gsrc[t] = Bw + (size_t)row * K + cbx * 8;
            ldst[t] = lsB + jj * 512;
        }
    }

    const int fr   = lane & 15;
    const int ks   = lane >> 4;
    const int slot = ks ^ ((fr >> 1) & 3);
    const __bf16* ardp[4];
    const __bf16* brdp[4];
#pragma unroll
    for (int i = 0; i < 4; ++i) {
        ardp[i] = lsA + (wm * 64 + i * 16 + fr) * 32 + slot * 8;
        brdp[i] = lsB + (wn * 64 + i * 16 + fr) * 32 + slot * 8;
    }

    floatx4 acc[4][4];
    const floatx4 vzero = {0.f, 0.f, 0.f, 0.f};
#pragma unroll
    for (int mi = 0; mi < 4; ++mi)
#pragma unroll
        for (int ni = 0; ni < 4; ++ni) acc[mi][ni] = vzero;

    const int nk = K >> 5;
    int limit = (klm * bn + kla) >> kls;
    if (limit > nk) limit = nk;
    const int iters = limit + ((tail && limit < nk) ? 1 : 0);

    for (int it = 0; it < iters; ++it) {
        const int kt = (it < limit ? it : nk - 1) << 5;
        __syncthreads();
#pragma unroll
        for (int t = 0; t < 4; ++t)
            load_lds16((const void*)(gsrc[t] + kt), (void*)ldst[t]);
        __syncthreads();
        bf16x8 af[4], bf[4];
#pragma unroll
        for (int i = 0; i < 4; ++i) af[i] = *(const bf16x8*)ardp[i];
#pragma unroll
        for (int i = 0; i < 4; ++i) bf[i] = *(const bf16x8*)brdp[i];
#pragma unroll
        for (int mi = 0; mi < 4; ++mi)
#pragma unroll
            for (int ni = 0; ni < 4; ++ni)
                acc[mi][ni] = __builtin_amdgcn_mfma_f32_16x16x32_bf16(
                    af[mi], bf[ni], acc[mi][ni], 0, 0, 0);
    }

    const int cn  = lane & 15;
    const int cr4 = (lane >> 4) * 4;
#pragma unroll
    for (int ni = 0; ni < 4; ++ni) {
        int col = bn * 128 + wn * 64 + ni * 16 + cn;
        float bv = bias[PERMBIAS ? invp(col) : col];
#pragma unroll
        for (int mi = 0; mi < 4; ++mi) {
            int row0 = bm * 128 + wm * 64 + mi * 16 + cr4;
#pragma unroll
            for (int q = 0; q < 4; ++q) {
                float v = acc[mi][ni][q] + bv;
                if (RELU) v = fmaxf(v, 0.f);
                if (TLAYOUT) {
                    // b = row0+q; b>>6 = bm*2+wm; b&63 = mi*16+cr4+q
                    size_t addr = (size_t)(bm * 2 + wm) * ((size_t)N * 64)
                                + (size_t)col * 64 + (mi * 16 + cr4 + q);
                    ((__bf16*)Cout)[addr] = (__bf16)v;
                } else if (OBF16) {
                    ((__bf16*)Cout)[(size_t)(row0 + q) * N + col] = (__bf16)v;
                } else {
                    ((float*)Cout)[(size_t)(row0 + q) * N + col] = v;
                }
            }
        }
    }
}

// ---------------------------------------------------------------------------
// Segment-parallel log-semiring chain, one thread per (batch, segment).
// theta (bf16) in batch-interleaved layout th2[b>>6][f][b&63].
// ---------------------------------------------------------------------------
__global__ __launch_bounds__(256)
void chain_seg(const __bf16* __restrict__ th2,  // [128][4096][64] bf16
               const float* __restrict__ x,     // [8192,128]
               float* __restrict__ P)           // [8192,18,16]
{
    const int b = blockIdx.x * 256 + threadIdx.x;
    const int s = blockIdx.y;                    // 0..17
    const int i0 = 1 + s * 7;
    const __bf16* tp = th2 + (size_t)(b >> 6) * (4096 * 64) + (b & 63)
                           + (size_t)i0 * 32 * 64;
    const float* xp = x + (size_t)b * 128 + i0;

    const float LOG2E = 1.4426950408889634f;
    const float C0    = 2.3052328943245633f;     // 0.5*log(2pi) + log(4)

    float M[4][4];
#pragma unroll
    for (int r = 0; r < 4; ++r)
#pragma unroll
        for (int c = 0; c < 4; ++c) M[r][c] = (r == c) ? 0.f : -1e30f;

    for (int ii = 0; ii < 7; ++ii) {
        float mu[16], al[16];
#pragma unroll
        for (int j = 0; j < 16; ++j) mu[j] = (float)tp[(size_t)j * 64];
#pragma unroll
        for (int j = 0; j < 16; ++j) al[j] = (float)tp[(size_t)(16 + j) * 64];
        float xv = xp[ii];
        tp += 32 * 64;
        float lp[16];
#pragma unroll
        for (int j = 0; j < 16; ++j) {
            float a = al[j];
            float e = fexp2(-a * LOG2E);
            float z = (xv - mu[j]) * e;
            lp[j] = (-0.5f * z * z - a - C0) * LOG2E;
        }
        float Mn[4][4];
#pragma unroll
        for (int r = 0; r < 4; ++r)
#pragma unroll
            for (int c = 0; c < 4; ++c) {
                float a0 = M[r][0] + lp[0 * 4 + c];
                float a1 = M[r][1] + lp[1 * 4 + c];
                float a2 = M[r][2] + lp[2 * 4 + c];
                float a3 = M[r][3] + lp[3 * 4 + c];
                float mx = fmaxf(fmaxf(a0, a1), fmaxf(a2, a3));
                float sm = fexp2(a0 - mx) + fexp2(a1 - mx) +
                           fexp2(a2 - mx) + fexp2(a3 - mx);
                Mn[r][c] = mx + flog2(sm);
            }
#pragma unroll
        for (int r = 0; r < 4; ++r)
#pragma unroll
            for (int c = 0; c < 4; ++c) M[r][c] = Mn[r][c];
    }

    float* pb = P + ((size_t)b * 18 + s) * 16;
#pragma unroll
    for (int r = 0; r < 4; ++r) {
        floatx4 o = {M[r][0], M[r][1], M[r][2], M[r][3]};
        *(floatx4*)(pb + r * 4) = o;
    }
}

// ---------------------------------------------------------------------------
// Combine: fold 18 segment matrices + first/last boundary vectors per batch.
// ---------------------------------------------------------------------------
__global__ __launch_bounds__(256)
void chain_fin(const __bf16* __restrict__ th2,  // [128][4096][64] bf16
               const float* __restrict__ x,     // [8192,128]
               const float* __restrict__ P,     // [8192,18,16]
               float* __restrict__ out)         // [8192]
{
    const int tid  = threadIdx.x;
    const int lane = tid & 63;
    const int r    = lane & 3;
    const int l0   = lane & 60;
    const int b    = blockIdx.x * 64 + (tid >> 2);
    const __bf16* tb = th2 + (size_t)(b >> 6) * (4096 * 64) + (b & 63);

    const float LOG2E = 1.4426950408889634f;
    const float LN2   = 0.6931471805599453f;
    const float C0    = 2.3052328943245633f;

    const float* Pb = P + (size_t)b * 288;       // 18*16
    floatx4 m0 = *(const floatx4*)(Pb + r * 4);
    float M[4] = {m0[0], m0[1], m0[2], m0[3]};

#pragma unroll
    for (int s = 1; s < 18; ++s) {
        floatx4 lr = *(const floatx4*)(Pb + s * 16 + r * 4);
        float Mn[4];
#pragma unroll
        for (int c = 0; c < 4; ++c) {
            float a0 = M[0] + __shfl(lr[c], l0 + 0);
            float a1 = M[1] + __shfl(lr[c], l0 + 1);
            float a2 = M[2] + __shfl(lr[c], l0 + 2);
            float a3 = M[3] + __shfl(lr[c], l0 + 3);
            float mx = fmaxf(fmaxf(a0, a1), fmaxf(a2, a3));
            float sm = fexp2(a0 - mx) + fexp2(a1 - mx) + fexp2(a2 - mx) + fexp2(a3 - mx);
            Mn[c] = mx + flog2(sm);
        }
#pragma unroll
        for (int k = 0; k < 4; ++k) M[k] = Mn[k];
    }

    float xl = x[(size_t)b * 128 + 127];
    float a[4];
#pragma unroll
    for (int c = 0; c < 4; ++c) {
        float mu_ = (float)tb[(size_t)(4064 + c * 4) * 64];
        float al_ = (float)tb[(size_t)(4064 + 16 + c * 4) * 64];
        float e = fexp2(-al_ * LOG2E);
        float z = (xl - mu_) * e;
        float lp2 = (-0.5f * z * z - al_ - C0) * LOG2E;
        a[c] = M[c] + lp2;
    }
    float mx = fmaxf(fmaxf(a[0], a[1]), fmaxf(a[2], a[3]));
    float tr = mx + flog2(fexp2(a[0] - mx) + fexp2(a[1] - mx) +
                          fexp2(a[2] - mx) + fexp2(a[3] - mx));

    float x0  = x[(size_t)b * 128];
    float muf = (float)tb[(size_t)r * 64];
    float alf = (float)tb[(size_t)(16 + r) * 64];
    float ef = fexp2(-alf * LOG2E);
    float zf = (x0 - muf) * ef;
    float f2 = (-0.5f * zf * zf - alf - C0) * LOG2E;
    float v = f2 + tr;
    float m1 = fmaxf(v, __shfl_xor(v, 1));
    float m2 = fmaxf(m1, __shfl_xor(m1, 2));
    float sum = fexp2(v - m2);
    sum += __shfl_xor(sum, 1);
    sum += __shfl_xor(sum, 2);
    if (r == 0) out[b] = (m2 + flog2(sum)) * LN2;
}

// ---------------------------------------------------------------------------
extern "C" void kernel_launch(void* const* d_in, const int* in_sizes, int n_in,
                              void* d_out, int out_size, void* d_ws, size_t ws_size,
                              hipStream_t stream)
{
    (void)in_sizes; (void)n_in; (void)out_size; (void)ws_size;
    const float* x  = (const float*)d_in[0];
    const float* W0 = (const float*)d_in[1];
    const float* b0 = (const float*)d_in[2];
    const float* W1 = (const float*)d_in[3];
    const float* b1 = (const float*)d_in[4];
    const float* W2 = (const float*)d_in[5];
    const float* b2 = (const float*)d_in[6];
    const float* W3 = (const float*)d_in[7];
    const float* b3 = (const float*)d_in[8];

    char* ws = (char*)d_ws;
    size_t off = 0;
    auto alloc = [&](size_t bytes) { char* p = ws + off; off += bytes; return p; };
    __bf16* xb  = (__bf16*)alloc((size_t)8192 * 128 * 2);    // 2 MB
    __bf16* w0m = (__bf16*)alloc((size_t)2048 * 128 * 2);    // 0.5 MB
    __bf16* w1m = (__bf16*)alloc((size_t)2048 * 2048 * 2);   // 8 MB
    __bf16* w2m = (__bf16*)alloc((size_t)2048 * 2048 * 2);   // 8 MB
    __bf16* w3m = (__bf16*)alloc((size_t)4096 * 2048 * 2);   // 16 MB
    __bf16* h1  = (__bf16*)alloc((size_t)8192 * 2048 * 2);   // 32 MB
    __bf16* h2  = (__bf16*)alloc((size_t)8192 * 2048 * 2);   // 32 MB
    __bf16* th  = (__bf16*)alloc((size_t)8192 * 4096 * 2);   // 64 MB (batch-interleaved)
    __bf16* h3  = h1;            // h1 dead after GEMM2; reuse for h3
    float*  P   = (float*)h2;    // h2 dead after GEMM3; P = 9.4 MB << 32 MB

    // fused masked+degree-sorted weight prep (LDS permute; coalesced both sides)
    prep_all<<<8832, 256, 0, stream>>>(x, W0, W1, W2, W3, xb, w0m, w1m, w2m, w3m);

    // GEMM0: K=128 natural cols; limit = (8*bn+39)>>5 chunks, no tail
    gemm_bt<true, true, false, true><<<dim3(64, 16), 256, 0, stream>>>(
        xb, w0m, b0, h1, 2048, 128, 8, 39, 5, 0);
    // GEMM1/2: sorted K; limit = 4*bn+4 chunks (+tail)
    gemm_bt<true, true, false, true><<<dim3(64, 16), 256, 0, stream>>>(
        h1, w1m, b1, h2, 2048, 2048, 4, 4, 0, 1);
    gemm_bt<true, true, false, true><<<dim3(64, 16), 256, 0, stream>>>(
        h2, w2m, b2, h3, 2048, 2048, 4, 4, 0, 1);
    // GEMM3: theta bf16 (natural N, TLAYOUT store); limit = 2*bn+2 chunks (+tail)
    gemm_bt<false, false, true, false><<<dim3(64, 32), 256, 0, stream>>>(
        h3, w3m, b3, th, 4096, 2048, 2, 2, 0, 1);

    // segment-parallel log-semiring chain
    chain_seg<<<dim3(32, 18), 256, 0, stream>>>(th, x, P);
    chain_fin<<<128, 256, 0, stream>>>(th, x, P, (float*)d_out);
}

// Round 8
// 323.789 us; speedup vs baseline: 1.5330x; 1.1044x over previous
//
#include <hip/hip_runtime.h>
#include <hip/hip_bf16.h>
#include <cstdint>
#include <cstddef>

#define AS1 __attribute__((address_space(1)))
#define AS3 __attribute__((address_space(3)))

typedef __bf16 bf16x8 __attribute__((ext_vector_type(8)));
typedef float  floatx4 __attribute__((ext_vector_type(4)));

__device__ __forceinline__ void load_lds16(const void* g, void* l) {
    __builtin_amdgcn_global_load_lds((AS1 void*)g, (AS3 void*)l, 16, 0, 0);
}

__device__ __forceinline__ float fexp2(float x) { return __builtin_amdgcn_exp2f(x); }
__device__ __forceinline__ float flog2(float x) { return __builtin_amdgcn_logf(x); }

// Degree-sorted feature permutation for hidden layers (2048 feats, deg = f%127).
// sorted position p <-> feature f: p = (f%127)*16 + f/127 for f<2032 (=16*127),
// p = f for p>=2032. resp(p) = degree of the feature at sorted position p.
__device__ __forceinline__ int invp(int p) {
    return p < 2032 ? (p & 15) * 127 + (p >> 4) : p;
}
__device__ __forceinline__ int resp(int p) {
    return p < 2032 ? (p >> 4) : p - 2032;
}

// ---------------------------------------------------------------------------
// Prep v3: masks + fp32->bf16 + degree-sort, coalesced both sides via LDS.
// ---------------------------------------------------------------------------
__global__ __launch_bounds__(256)
void prep_all(const float* __restrict__ x,  const float* __restrict__ W0,
              const float* __restrict__ W1, const float* __restrict__ W2,
              const float* __restrict__ W3,
              __bf16* __restrict__ xb,  __bf16* __restrict__ w0m,
              __bf16* __restrict__ w1m, __bf16* __restrict__ w2m,
              __bf16* __restrict__ w3m)
{
    __shared__ float lds[2048];
    const int blk = blockIdx.x;
    const int tid = threadIdx.x;
    const int t8  = tid * 8;

    if (blk < 640) {                       // direct regions (x, W0)
        bf16x8 o;
        if (blk < 512) {                   // x copy
            size_t base = (size_t)blk * 2048 + t8;
            floatx4 a = *(const floatx4*)(x + base);
            floatx4 b = *(const floatx4*)(x + base + 4);
#pragma unroll
            for (int j = 0; j < 4; ++j) { o[j] = (__bf16)a[j]; o[4 + j] = (__bf16)b[j]; }
            *(bf16x8*)(xb + base) = o;
        } else {                           // W0: dst[p_n][c] = W0[invp(p_n)][c] * mask
            long idx = (long)(blk - 512) * 2048 + t8;
            int p_n = (int)(idx >> 7);
            int c   = (int)(idx & 127);
            int dg  = resp(p_n);
            const float* s = W0 + (long)invp(p_n) * 128 + c;
            floatx4 a = *(const floatx4*)s;
            floatx4 b = *(const floatx4*)(s + 4);
#pragma unroll
            for (int j = 0; j < 8; ++j) {
                float v = j < 4 ? a[j] : b[j - 4];
                o[j] = (__bf16)((dg >= c + j) ? v : 0.0f);
            }
            *(bf16x8*)(w0m + idx) = o;
        }
        return;
    }

    // permuted-column regions: one dst row per block
    const float* srow; __bf16* drow; int deg_n; bool strict;
    if (blk < 2688) {
        int p_n = blk - 640;
        srow = W1 + (size_t)invp(p_n) * 2048; drow = w1m + (size_t)p_n * 2048;
        deg_n = resp(p_n); strict = false;
    } else if (blk < 4736) {
        int p_n = blk - 2688;
        srow = W2 + (size_t)invp(p_n) * 2048; drow = w2m + (size_t)p_n * 2048;
        deg_n = resp(p_n); strict = false;
    } else {
        int n = blk - 4736;
        srow = W3 + (size_t)n * 2048; drow = w3m + (size_t)n * 2048;
        deg_n = n >> 5; strict = true;
    }
    floatx4 a = *(const floatx4*)(srow + t8);
    floatx4 b = *(const floatx4*)(srow + t8 + 4);
    *(floatx4*)&lds[t8]     = a;
    *(floatx4*)&lds[t8 + 4] = b;
    __syncthreads();
    bf16x8 o;
#pragma unroll
    for (int j = 0; j < 8; ++j) {
        int p = t8 + j;
        float v = lds[invp(p)];
        int dg = resp(p);
        bool keep = strict ? (deg_n > dg) : (deg_n >= dg);
        o[j] = (__bf16)(keep ? v : 0.0f);
    }
    *(bf16x8*)(drow + t8) = o;
}

// ---------------------------------------------------------------------------
// bf16 MFMA GEMM, BK=64, C[M,N] = A[M,K] * Bw[N,K]^T + bias, optional ReLU.
// K-SKIP (64-units): chunks [0,limit) + tail chunk nk-1 (low-deg leftovers).
// LPT: bn reversed so longest (largest-limit) tiles dispatch first.
// TLAYOUT: store bf16 batch-interleaved th2[b>>6][col][b&63].
// PERMBIAS: bias indexed through invp(col).
// ---------------------------------------------------------------------------
template <bool RELU, bool OBF16, bool TLAYOUT, bool PERMBIAS>
__global__ __launch_bounds__(256, 3)
void gemm_bt(const __bf16* __restrict__ A, const __bf16* __restrict__ Bw,
             const float* __restrict__ bias, void* __restrict__ Cout,
             int N, int K, int klm, int kla, int kls, int tail)
{
    __shared__ __align__(16) __bf16 lsA[128 * 64];   // 16 KB
    __shared__ __align__(16) __bf16 lsB[128 * 64];   // 16 KB
    const int tid  = threadIdx.x;
    const int wave = tid >> 6;
    const int lane = tid & 63;
    const int bm = blockIdx.x;
    const int bn = (gridDim.y - 1) - blockIdx.y;     // LPT order
    const int wm = wave >> 1, wn = wave & 1;

    // staging: 32 chunks of 1KB (A:0..15, B:16..31), 8 per wave.
    // chunk j covers rows [8j,8j+8); DMA puts lane l at LDS slot (l&7), so we
    // read global col-block (l&7)^(l>>3) -> LDS[row][s] = global[row][s^(row&7)]
    const int r8 = lane >> 3;
    const int cb = (lane & 7) ^ r8;
    const __bf16* gsrc[8];
    __bf16* ldst[8];
#pragma unroll
    for (int t = 0; t < 8; ++t) {
        int j = wave * 8 + t;
        if (j < 16) {
            int row = bm * 128 + j * 8 + r8;
            gsrc[t] = A + (size_t)row * K + cb * 8;
            ldst[t] = lsA + j * 512;
        } else {
            int jj = j - 16;
            int row = bn * 128 + jj * 8 + r8;
            gsrc[t] = Bw + (size_t)row * K + cb * 8;
            ldst[t] = lsB + jj * 512;
        }
    }

    // frag reads: row fr, global k-block g=kk*4+ks lives at LDS slot g^(fr&7)
    const int fr  = lane & 15;
    const int ks  = lane >> 4;
    const int sx  = fr & 7;
    const int sl0 = ((ks)     ^ sx) * 8;
    const int sl1 = ((4 + ks) ^ sx) * 8;
    const __bf16* arow[4];
    const __bf16* brow[4];
#pragma unroll
    for (int i = 0; i < 4; ++i) {
        arow[i] = lsA + (wm * 64 + i * 16 + fr) * 64;
        brow[i] = lsB + (wn * 64 + i * 16 + fr) * 64;
    }

    floatx4 acc[4][4];
    const floatx4 vzero = {0.f, 0.f, 0.f, 0.f};
#pragma unroll
    for (int mi = 0; mi < 4; ++mi)
#pragma unroll
        for (int ni = 0; ni < 4; ++ni) acc[mi][ni] = vzero;

    const int nk = K >> 6;
    int limit = (klm * bn + kla) >> kls;
    if (limit > nk) limit = nk;
    const int iters = limit + ((tail && limit < nk) ? 1 : 0);

    for (int it = 0; it < iters; ++it) {
        const int kt = (it < limit ? it : nk - 1) << 6;
        __syncthreads();
#pragma unroll
        for (int t = 0; t < 8; ++t)
            load_lds16((const void*)(gsrc[t] + kt), (void*)ldst[t]);
        __syncthreads();
        bf16x8 af[4], bf[4];
#pragma unroll
        for (int i = 0; i < 4; ++i) af[i] = *(const bf16x8*)(arow[i] + sl0);
#pragma unroll
        for (int i = 0; i < 4; ++i) bf[i] = *(const bf16x8*)(brow[i] + sl0);
#pragma unroll
        for (int mi = 0; mi < 4; ++mi)
#pragma unroll
            for (int ni = 0; ni < 4; ++ni)
                acc[mi][ni] = __builtin_amdgcn_mfma_f32_16x16x32_bf16(
                    af[mi], bf[ni], acc[mi][ni], 0, 0, 0);
#pragma unroll
        for (int i = 0; i < 4; ++i) af[i] = *(const bf16x8*)(arow[i] + sl1);
#pragma unroll
        for (int i = 0; i < 4; ++i) bf[i] = *(const bf16x8*)(brow[i] + sl1);
#pragma unroll
        for (int mi = 0; mi < 4; ++mi)
#pragma unroll
            for (int ni = 0; ni < 4; ++ni)
                acc[mi][ni] = __builtin_amdgcn_mfma_f32_16x16x32_bf16(
                    af[mi], bf[ni], acc[mi][ni], 0, 0, 0);
    }

    const int cn  = lane & 15;
    const int cr4 = (lane >> 4) * 4;
#pragma unroll
    for (int ni = 0; ni < 4; ++ni) {
        int col = bn * 128 + wn * 64 + ni * 16 + cn;
        float bv = bias[PERMBIAS ? invp(col) : col];
#pragma unroll
        for (int mi = 0; mi < 4; ++mi) {
            int row0 = bm * 128 + wm * 64 + mi * 16 + cr4;
#pragma unroll
            for (int q = 0; q < 4; ++q) {
                float v = acc[mi][ni][q] + bv;
                if (RELU) v = fmaxf(v, 0.f);
                if (TLAYOUT) {
                    // b = row0+q; b>>6 = bm*2+wm; b&63 = mi*16+cr4+q
                    size_t addr = (size_t)(bm * 2 + wm) * ((size_t)N * 64)
                                + (size_t)col * 64 + (mi * 16 + cr4 + q);
                    ((__bf16*)Cout)[addr] = (__bf16)v;
                } else if (OBF16) {
                    ((__bf16*)Cout)[(size_t)(row0 + q) * N + col] = (__bf16)v;
                } else {
                    ((float*)Cout)[(size_t)(row0 + q) * N + col] = v;
                }
            }
        }
    }
}

// ---------------------------------------------------------------------------
// Segment-parallel log-semiring chain, one thread per (batch, segment).
// theta (bf16) in batch-interleaved layout th2[b>>6][f][b&63].
// ---------------------------------------------------------------------------
__global__ __launch_bounds__(256)
void chain_seg(const __bf16* __restrict__ th2,  // [128][4096][64] bf16
               const float* __restrict__ x,     // [8192,128]
               float* __restrict__ P)           // [8192,18,16]
{
    const int b = blockIdx.x * 256 + threadIdx.x;
    const int s = blockIdx.y;                    // 0..17
    const int i0 = 1 + s * 7;
    const __bf16* tp = th2 + (size_t)(b >> 6) * (4096 * 64) + (b & 63)
                           + (size_t)i0 * 32 * 64;
    const float* xp = x + (size_t)b * 128 + i0;

    const float LOG2E = 1.4426950408889634f;
    const float C0    = 2.3052328943245633f;     // 0.5*log(2pi) + log(4)

    float M[4][4];
#pragma unroll
    for (int r = 0; r < 4; ++r)
#pragma unroll
        for (int c = 0; c < 4; ++c) M[r][c] = (r == c) ? 0.f : -1e30f;

    for (int ii = 0; ii < 7; ++ii) {
        float mu[16], al[16];
#pragma unroll
        for (int j = 0; j < 16; ++j) mu[j] = (float)tp[(size_t)j * 64];
#pragma unroll
        for (int j = 0; j < 16; ++j) al[j] = (float)tp[(size_t)(16 + j) * 64];
        float xv = xp[ii];
        tp += 32 * 64;
        float lp[16];
#pragma unroll
        for (int j = 0; j < 16; ++j) {
            float a = al[j];
            float e = fexp2(-a * LOG2E);
            float z = (xv - mu[j]) * e;
            lp[j] = (-0.5f * z * z - a - C0) * LOG2E;
        }
        float Mn[4][4];
#pragma unroll
        for (int r = 0; r < 4; ++r)
#pragma unroll
            for (int c = 0; c < 4; ++c) {
                float a0 = M[r][0] + lp[0 * 4 + c];
                float a1 = M[r][1] + lp[1 * 4 + c];
                float a2 = M[r][2] + lp[2 * 4 + c];
                float a3 = M[r][3] + lp[3 * 4 + c];
                float mx = fmaxf(fmaxf(a0, a1), fmaxf(a2, a3));
                float sm = fexp2(a0 - mx) + fexp2(a1 - mx) +
                           fexp2(a2 - mx) + fexp2(a3 - mx);
                Mn[r][c] = mx + flog2(sm);
            }
#pragma unroll
        for (int r = 0; r < 4; ++r)
#pragma unroll
            for (int c = 0; c < 4; ++c) M[r][c] = Mn[r][c];
    }

    float* pb = P + ((size_t)b * 18 + s) * 16;
#pragma unroll
    for (int r = 0; r < 4; ++r) {
        floatx4 o = {M[r][0], M[r][1], M[r][2], M[r][3]};
        *(floatx4*)(pb + r * 4) = o;
    }
}

// ---------------------------------------------------------------------------
// Combine: fold 18 segment matrices + first/last boundary vectors per batch.
// ---------------------------------------------------------------------------
__global__ __launch_bounds__(256)
void chain_fin(const __bf16* __restrict__ th2,  // [128][4096][64] bf16
               const float* __restrict__ x,     // [8192,128]
               const float* __restrict__ P,     // [8192,18,16]
               float* __restrict__ out)         // [8192]
{
    const int tid  = threadIdx.x;
    const int lane = tid & 63;
    const int r    = lane & 3;
    const int l0   = lane & 60;
    const int b    = blockIdx.x * 64 + (tid >> 2);
    const __bf16* tb = th2 + (size_t)(b >> 6) * (4096 * 64) + (b & 63);

    const float LOG2E = 1.4426950408889634f;
    const float LN2   = 0.6931471805599453f;
    const float C0    = 2.3052328943245633f;

    const float* Pb = P + (size_t)b * 288;       // 18*16
    floatx4 m0 = *(const floatx4*)(Pb + r * 4);
    float M[4] = {m0[0], m0[1], m0[2], m0[3]};

#pragma unroll
    for (int s = 1; s < 18; ++s) {
        floatx4 lr = *(const floatx4*)(Pb + s * 16 + r * 4);
        float Mn[4];
#pragma unroll
        for (int c = 0; c < 4; ++c) {
            float a0 = M[0] + __shfl(lr[c], l0 + 0);
            float a1 = M[1] + __shfl(lr[c], l0 + 1);
            float a2 = M[2] + __shfl(lr[c], l0 + 2);
            float a3 = M[3] + __shfl(lr[c], l0 + 3);
            float mx = fmaxf(fmaxf(a0, a1), fmaxf(a2, a3));
            float sm = fexp2(a0 - mx) + fexp2(a1 - mx) + fexp2(a2 - mx) + fexp2(a3 - mx);
            Mn[c] = mx + flog2(sm);
        }
#pragma unroll
        for (int k = 0; k < 4; ++k) M[k] = Mn[k];
    }

    float xl = x[(size_t)b * 128 + 127];
    float a[4];
#pragma unroll
    for (int c = 0; c < 4; ++c) {
        float mu_ = (float)tb[(size_t)(4064 + c * 4) * 64];
        float al_ = (float)tb[(size_t)(4064 + 16 + c * 4) * 64];
        float e = fexp2(-al_ * LOG2E);
        float z = (xl - mu_) * e;
        float lp2 = (-0.5f * z * z - al_ - C0) * LOG2E;
        a[c] = M[c] + lp2;
    }
    float mx = fmaxf(fmaxf(a[0], a[1]), fmaxf(a[2], a[3]));
    float tr = mx + flog2(fexp2(a[0] - mx) + fexp2(a[1] - mx) +
                          fexp2(a[2] - mx) + fexp2(a[3] - mx));

    float x0  = x[(size_t)b * 128];
    float muf = (float)tb[(size_t)r * 64];
    float alf = (float)tb[(size_t)(16 + r) * 64];
    float ef = fexp2(-alf * LOG2E);
    float zf = (x0 - muf) * ef;
    float f2 = (-0.5f * zf * zf - alf - C0) * LOG2E;
    float v = f2 + tr;
    float m1 = fmaxf(v, __shfl_xor(v, 1));
    float m2 = fmaxf(m1, __shfl_xor(m1, 2));
    float sum = fexp2(v - m2);
    sum += __shfl_xor(sum, 1);
    sum += __shfl_xor(sum, 2);
    if (r == 0) out[b] = (m2 + flog2(sum)) * LN2;
}

// ---------------------------------------------------------------------------
extern "C" void kernel_launch(void* const* d_in, const int* in_sizes, int n_in,
                              void* d_out, int out_size, void* d_ws, size_t ws_size,
                              hipStream_t stream)
{
    (void)in_sizes; (void)n_in; (void)out_size; (void)ws_size;
    const float* x  = (const float*)d_in[0];
    const float* W0 = (const float*)d_in[1];
    const float* b0 = (const float*)d_in[2];
    const float* W1 = (const float*)d_in[3];
    const float* b1 = (const float*)d_in[4];
    const float* W2 = (const float*)d_in[5];
    const float* b2 = (const float*)d_in[6];
    const float* W3 = (const float*)d_in[7];
    const float* b3 = (const float*)d_in[8];

    char* ws = (char*)d_ws;
    size_t off = 0;
    auto alloc = [&](size_t bytes) { char* p = ws + off; off += bytes; return p; };
    __bf16* xb  = (__bf16*)alloc((size_t)8192 * 128 * 2);    // 2 MB
    __bf16* w0m = (__bf16*)alloc((size_t)2048 * 128 * 2);    // 0.5 MB
    __bf16* w1m = (__bf16*)alloc((size_t)2048 * 2048 * 2);   // 8 MB
    __bf16* w2m = (__bf16*)alloc((size_t)2048 * 2048 * 2);   // 8 MB
    __bf16* w3m = (__bf16*)alloc((size_t)4096 * 2048 * 2);   // 16 MB
    __bf16* h1  = (__bf16*)alloc((size_t)8192 * 2048 * 2);   // 32 MB
    __bf16* h2  = (__bf16*)alloc((size_t)8192 * 2048 * 2);   // 32 MB
    __bf16* th  = (__bf16*)alloc((size_t)8192 * 4096 * 2);   // 64 MB (batch-interleaved)
    __bf16* h3  = h1;            // h1 dead after GEMM2; reuse for h3
    float*  P   = (float*)h2;    // h2 dead after GEMM3; P = 9.4 MB << 32 MB

    // fused masked+degree-sorted weight prep (LDS permute; coalesced both sides)
    prep_all<<<8832, 256, 0, stream>>>(x, W0, W1, W2, W3, xb, w0m, w1m, w2m, w3m);

    // GEMM0: K=128 (nk=2); limit = (8*bn+71)>>6, no tail
    gemm_bt<true, true, false, true><<<dim3(64, 16), 256, 0, stream>>>(
        xb, w0m, b0, h1, 2048, 128, 8, 71, 6, 0);
    // GEMM1/2: sorted K (nk=32); limit = 2*bn+2 (+tail)
    gemm_bt<true, true, false, true><<<dim3(64, 16), 256, 0, stream>>>(
        h1, w1m, b1, h2, 2048, 2048, 2, 2, 0, 1);
    gemm_bt<true, true, false, true><<<dim3(64, 16), 256, 0, stream>>>(
        h2, w2m, b2, h3, 2048, 2048, 2, 2, 0, 1);
    // GEMM3: theta bf16 (natural N, TLAYOUT store, nk=32); limit = bn+1 (+tail)
    gemm_bt<false, false, true, false><<<dim3(64, 32), 256, 0, stream>>>(
        h3, w3m, b3, th, 4096, 2048, 1, 1, 0, 1);

    // segment-parallel log-semiring chain
    chain_seg<<<dim3(32, 18), 256, 0, stream>>>(th, x, P);
    chain_fin<<<128, 256, 0, stream>>>(th, x, P, (float*)d_out);
}